// Round 7
// baseline (47.604 us; speedup 1.0000x reference)
//
#include <hip/hip_runtime.h>
#include <math.h>

// Input:  x (16, 31, 256, 256) float32
// Output: sqrt(v^2 + h^2 + 1e-6), v = x[y+1]-x[y-1], h = x[:,x+1]-x[:,x-1],
// zero padding at the borders.
//
// R7: cache-policy inversion. R6 cached the INPUT in L3 (FETCH 63MB < 130MB)
// and streamed the OUTPUT to HBM (WRITE 127MB every replay). But writes are
// the bigger HBM component. Here: nontemporal LOADS (input streams from HBM,
// no L3 allocation) + REGULAR stores (output 124 MiB becomes sole L3
// resident; write-back means each replay overwrites dirty lines in-cache and
// steady-state HBM write traffic collapses). R4 failed because in+out=248MiB
// thrashed TOGETHER; this gives the output exclusive L3 occupancy.
// Everything else identical to R6 (STRIP=8, 256-thd blocks, XCD swizzle,
// sched_barrier load batch, v_sqrt).

#define IMG_H 256
#define IMG_W 256
#define EPS   1e-6f
#define STRIP 8                    // output rows per wave/lane
#define WAVES_PER_BLOCK 4
#define ROWS_PER_BLOCK (STRIP * WAVES_PER_BLOCK)   // 32
#define BANDS (IMG_H / ROWS_PER_BLOCK)             // 8

typedef float f32x4 __attribute__((ext_vector_type(4)));

__global__ __launch_bounds__(256) void grad_mag_kernel(
    const float* __restrict__ in, float* __restrict__ out)
{
    const int tid  = threadIdx.x;
    const int lane = tid & 63;
    const int wv   = tid >> 6;                    // wave within block: 0..3

    // XCD-chunked swizzle (bijective: gridDim.x = 3968 divisible by 8).
    const int chunk = gridDim.x >> 3;
    const int sid   = (blockIdx.x & 7) * chunk + (blockIdx.x >> 3);

    const int band        = sid & (BANDS - 1);
    const long long plane = sid >> 3;             // 0..495

    const int y0 = band * ROWS_PER_BLOCK + wv * STRIP;  // first output row
    const int x0 = lane * 4;

    const float* __restrict__ p = in  + plane * (long long)(IMG_H * IMG_W) + x0;
    float*       __restrict__ q = out + plane * (long long)(IMG_H * IMG_W) + x0;

    // Load rows y0-1 .. y0+STRIP unconditionally from clamped addresses
    // (branch-free, back-to-back issue -> 10 outstanding loads per lane).
    // Nontemporal: input is read once per replay; keep it OUT of L3 so the
    // output can own the cache.
    f32x4 r[STRIP + 2];
    #pragma unroll
    for (int i = 0; i < STRIP + 2; ++i) {
        const int y  = y0 - 1 + i;
        const int yc = y < 0 ? 0 : (y > IMG_H - 1 ? IMG_H - 1 : y);
        r[i] = __builtin_nontemporal_load(
                   reinterpret_cast<const f32x4*>(p + (long long)yc * IMG_W));
    }
    // Keep the load batch together — do not let compute interleave upward.
    __builtin_amdgcn_sched_barrier(0);

    #pragma unroll
    for (int i = 0; i < STRIP + 2; ++i) {
        const int y = y0 - 1 + i;
        if (y < 0 || y > IMG_H - 1) r[i] = (f32x4)0.f;
    }

    #pragma unroll
    for (int i = 0; i < STRIP; ++i) {
        const f32x4 up  = r[i];
        const f32x4 cur = r[i + 1];
        const f32x4 dn  = r[i + 2];

        // Horizontal neighbors across lanes (wave spans exactly one row).
        float left  = __shfl_up(cur.w, 1);
        float right = __shfl_down(cur.x, 1);
        if (lane == 0)  left  = 0.f;     // zero pad at x = -1
        if (lane == 63) right = 0.f;     // zero pad at x = 256

        f32x4 h, v, o;
        h.x = cur.y - left;
        h.y = cur.z - cur.x;
        h.z = cur.w - cur.y;
        h.w = right - cur.z;
        v = dn - up;

        o.x = __builtin_amdgcn_sqrtf(v.x * v.x + h.x * h.x + EPS);
        o.y = __builtin_amdgcn_sqrtf(v.y * v.y + h.y * h.y + EPS);
        o.z = __builtin_amdgcn_sqrtf(v.z * v.z + h.z * h.z + EPS);
        o.w = __builtin_amdgcn_sqrtf(v.w * v.w + h.w * h.w + EPS);

        // Regular (cached, write-back) store — output owns the L3.
        *reinterpret_cast<f32x4*>(q + (long long)(y0 + i) * IMG_W) = o;
    }
}

extern "C" void kernel_launch(void* const* d_in, const int* in_sizes, int n_in,
                              void* d_out, int out_size, void* d_ws, size_t ws_size,
                              hipStream_t stream)
{
    const float* x = (const float*)d_in[0];
    float* out = (float*)d_out;

    const int planes = in_sizes[0] / (IMG_H * IMG_W);        // 16*31 = 496
    const int grid   = planes * BANDS;                       // 496 * 8 = 3968

    grad_mag_kernel<<<grid, 256, 0, stream>>>(x, out);
}

// Round 8
// 42.143 us; speedup vs baseline: 1.1296x; 1.1296x over previous
//
#include <hip/hip_runtime.h>
#include <math.h>

// Input:  x (16, 31, 256, 256) float32
// Output: sqrt(v^2 + h^2 + 1e-6), v = x[y+1]-x[y-1], h = x[:,x+1]-x[:,x-1],
// zero padding at the borders.
//
// R8: persistent-block pipelining. Grid halved to 1984 blocks; each block
// processes 2 adjacent band-strips in an unrolled loop. One generation of
// 7936 waves (~7.75/SIMD) stays resident for the whole kernel — no second
// dispatch ramp — and iteration-2 loads hoist above iteration-1 compute, so
// NT stores of strip A overlap strip B's loads (continuous DRAM read/write
// interleave, ~2x per-wave outstanding bytes). Keeps R6's proven pieces:
// cached loads + NT stores (R4/R7 proved any other policy costs ~7us),
// XCD-chunked swizzle, per-iteration sched_barrier load batch, v_sqrt.

#define IMG_H 256
#define IMG_W 256
#define EPS   1e-6f
#define STRIP 8                    // output rows per wave/lane
#define WAVES_PER_BLOCK 4
#define ROWS_PER_BLOCK (STRIP * WAVES_PER_BLOCK)   // 32
#define BANDS (IMG_H / ROWS_PER_BLOCK)             // 8
#define ITERS 2                    // band-strips per block

typedef float f32x4 __attribute__((ext_vector_type(4)));

__global__ __launch_bounds__(256) void grad_mag_kernel(
    const float* __restrict__ in, float* __restrict__ out)
{
    const int tid  = threadIdx.x;
    const int lane = tid & 63;
    const int wv   = tid >> 6;                    // wave within block: 0..3

    // XCD-chunked swizzle (bijective: gridDim.x = 1984 divisible by 8).
    const int chunk = gridDim.x >> 3;
    const int swz   = (blockIdx.x & 7) * chunk + (blockIdx.x >> 3);

    #pragma unroll
    for (int it = 0; it < ITERS; ++it) {
        const int sid = swz * ITERS + it;         // adjacent strips -> halo L2 reuse

        const int band        = sid & (BANDS - 1);
        const long long plane = sid >> 3;         // 0..495

        const int y0 = band * ROWS_PER_BLOCK + wv * STRIP;
        const int x0 = lane * 4;

        const float* __restrict__ p = in  + plane * (long long)(IMG_H * IMG_W) + x0;
        float*       __restrict__ q = out + plane * (long long)(IMG_H * IMG_W) + x0;

        // Load rows y0-1 .. y0+STRIP unconditionally from clamped addresses
        // (branch-free, back-to-back issue).
        f32x4 r[STRIP + 2];
        #pragma unroll
        for (int i = 0; i < STRIP + 2; ++i) {
            const int y  = y0 - 1 + i;
            const int yc = y < 0 ? 0 : (y > IMG_H - 1 ? IMG_H - 1 : y);
            r[i] = *reinterpret_cast<const f32x4*>(p + (long long)yc * IMG_W);
        }
        // Keep this load batch together; next iteration's loads may still
        // hoist above this iteration's compute (they don't cross a barrier).
        __builtin_amdgcn_sched_barrier(0);

        #pragma unroll
        for (int i = 0; i < STRIP + 2; ++i) {
            const int y = y0 - 1 + i;
            if (y < 0 || y > IMG_H - 1) r[i] = (f32x4)0.f;
        }

        #pragma unroll
        for (int i = 0; i < STRIP; ++i) {
            const f32x4 up  = r[i];
            const f32x4 cur = r[i + 1];
            const f32x4 dn  = r[i + 2];

            // Horizontal neighbors across lanes (wave spans one full row).
            float left  = __shfl_up(cur.w, 1);
            float right = __shfl_down(cur.x, 1);
            if (lane == 0)  left  = 0.f;     // zero pad at x = -1
            if (lane == 63) right = 0.f;     // zero pad at x = 256

            f32x4 h, v, o;
            h.x = cur.y - left;
            h.y = cur.z - cur.x;
            h.z = cur.w - cur.y;
            h.w = right - cur.z;
            v = dn - up;

            o.x = __builtin_amdgcn_sqrtf(v.x * v.x + h.x * h.x + EPS);
            o.y = __builtin_amdgcn_sqrtf(v.y * v.y + h.y * h.y + EPS);
            o.z = __builtin_amdgcn_sqrtf(v.z * v.z + h.z * h.z + EPS);
            o.w = __builtin_amdgcn_sqrtf(v.w * v.w + h.w * h.w + EPS);

            __builtin_nontemporal_store(
                o, reinterpret_cast<f32x4*>(q + (long long)(y0 + i) * IMG_W));
        }
    }
}

extern "C" void kernel_launch(void* const* d_in, const int* in_sizes, int n_in,
                              void* d_out, int out_size, void* d_ws, size_t ws_size,
                              hipStream_t stream)
{
    const float* x = (const float*)d_in[0];
    float* out = (float*)d_out;

    const int planes = in_sizes[0] / (IMG_H * IMG_W);        // 16*31 = 496
    const int grid   = planes * BANDS / ITERS;               // 1984
    
    grad_mag_kernel<<<grid, 256, 0, stream>>>(x, out);
}